// Round 3
// baseline (1389.048 us; speedup 1.0000x reference)
//
#include <hip/hip_runtime.h>
#include <math.h>

#define N_NODES 50000
#define N_EDGES 800000
#define MPAD 50048            // 391 * 128, so GEMM needs no M bounds checks
#define KPHYS 1024            // A2 physical row width: [hi(512) | lo(512)]
#define KVIRT 1536            // virtual K: hi*hi + lo*hi + hi*lo

// ---------------- bf16 helpers ----------------

__device__ __forceinline__ unsigned short bf16_rn(float f) {
    unsigned u = __float_as_uint(f);
    u += 0x7FFFu + ((u >> 16) & 1u);  // round-to-nearest-even
    return (unsigned short)(u >> 16);
}
__device__ __forceinline__ float bf16_f32(unsigned short h) {
    return __uint_as_float(((unsigned)h) << 16);
}

// ---------------- degree / CSR build ----------------

__global__ void zero_int_kernel(int* __restrict__ p, int n) {
    int i = blockIdx.x * blockDim.x + threadIdx.x;
    if (i < n) p[i] = 0;
}

__global__ void count_deg_kernel(const int* __restrict__ dst, int* __restrict__ deg) {
    int e = blockIdx.x * blockDim.x + threadIdx.x;
    if (e < N_EDGES) atomicAdd(&deg[dst[e]], 1);
}

__global__ void dinv_kernel(const int* __restrict__ deg, float* __restrict__ dinv) {
    int i = blockIdx.x * blockDim.x + threadIdx.x;
    if (i < N_NODES) dinv[i] = rsqrtf((float)deg[i] + 1.0f);  // +1 self-loop
}

__global__ __launch_bounds__(1024) void scan_kernel(const int* __restrict__ deg,
                                                    int* __restrict__ offsets,
                                                    int* __restrict__ cursor) {
    __shared__ int sm[1024];
    int t = threadIdx.x;
    int base = 0;
    if (t == 0) offsets[0] = 0;
    for (int start = 0; start < N_NODES; start += 1024) {
        int i = start + t;
        int v = (i < N_NODES) ? deg[i] : 0;
        sm[t] = v;
        __syncthreads();
        for (int off = 1; off < 1024; off <<= 1) {
            int x = (t >= off) ? sm[t - off] : 0;
            __syncthreads();
            sm[t] += x;
            __syncthreads();
        }
        if (i < N_NODES) {
            offsets[i + 1] = base + sm[t];
            cursor[i] = base + sm[t] - v;
        }
        base += sm[1023];
        __syncthreads();
    }
}

__global__ void fill_csr_kernel(const int* __restrict__ src, const int* __restrict__ dst,
                                int* __restrict__ cursor, int* __restrict__ csr_src,
                                float* __restrict__ csr_w, const float* __restrict__ dinv) {
    int e = blockIdx.x * blockDim.x + threadIdx.x;
    if (e < N_EDGES) {
        int s = src[e], d = dst[e];
        int p = atomicAdd(&cursor[d], 1);
        csr_src[p] = s;
        csr_w[p] = dinv[s] * dinv[d];
    }
}

// ---------------- split-bf16 MFMA GEMM ----------------

typedef __attribute__((ext_vector_type(8))) short bf16x8;
typedef __attribute__((ext_vector_type(4))) float floatx4;

#define GLL16(g, l)                                                                   \
    __builtin_amdgcn_global_load_lds((__attribute__((address_space(1))) const void*)(g), \
                                     (__attribute__((address_space(3))) void*)(l), 16, 0, 0)

__global__ __launch_bounds__(256) void gemm_split_bt(const unsigned short* __restrict__ A2,
                                                     const unsigned short* __restrict__ B2T,
                                                     float* __restrict__ C, int N) {
    __shared__ unsigned short As[128 * 32];  // [m][k], k contiguous
    __shared__ unsigned short Bs[128 * 32];  // [n][k], k contiguous

    const int t = threadIdx.x;
    const int lane = t & 63;
    const int quad = lane >> 4;
    const int l15 = lane & 15;
    const int w = t >> 6;
    const int wm = w & 1, wn = w >> 1;
    const int row0 = blockIdx.x * 128;
    const int col0 = blockIdx.y * 128;

    floatx4 acc[4][4];
#pragma unroll
    for (int i = 0; i < 4; i++)
#pragma unroll
        for (int j = 0; j < 4; j++) acc[i][j] = (floatx4){0.f, 0.f, 0.f, 0.f};

    const int sr = t >> 2;
    const int sk = (t & 3) * 8;
    const unsigned short* Arow0 = A2 + (size_t)(row0 + sr) * KPHYS + sk;
    const unsigned short* Arow1 = Arow0 + (size_t)64 * KPHYS;
    const unsigned short* Brow0 = B2T + (size_t)(col0 + sr) * KVIRT + sk;
    const unsigned short* Brow1 = Brow0 + (size_t)64 * KVIRT;
    unsigned short* lA0 = As + t * 8;
    unsigned short* lA1 = As + 2048 + t * 8;
    unsigned short* lB0 = Bs + t * 8;
    unsigned short* lB1 = Bs + 2048 + t * 8;

    for (int kb = 0; kb < KVIRT; kb += 32) {
        const int kA = (kb < KPHYS) ? kb : kb - KPHYS;  // virtual hi-replay wraps onto physical hi
        __syncthreads();
        GLL16(Arow0 + kA, lA0);
        GLL16(Arow1 + kA, lA1);
        GLL16(Brow0 + kb, lB0);
        GLL16(Brow1 + kb, lB1);
        __syncthreads();

        bf16x8 af[4], bf[4];
#pragma unroll
        for (int mt = 0; mt < 4; mt++)
            af[mt] = *(const bf16x8*)(As + (wm * 64 + mt * 16 + l15) * 32 + quad * 8);
#pragma unroll
        for (int nt = 0; nt < 4; nt++)
            bf[nt] = *(const bf16x8*)(Bs + (wn * 64 + nt * 16 + l15) * 32 + quad * 8);
#pragma unroll
        for (int mt = 0; mt < 4; mt++)
#pragma unroll
            for (int nt = 0; nt < 4; nt++)
                acc[mt][nt] = __builtin_amdgcn_mfma_f32_16x16x32_bf16(af[mt], bf[nt], acc[mt][nt], 0, 0, 0);
    }

#pragma unroll
    for (int mt = 0; mt < 4; mt++) {
#pragma unroll
        for (int r = 0; r < 4; r++) {
            int row = row0 + wm * 64 + mt * 16 + quad * 4 + r;
            float* Cp = C + (size_t)row * N + col0 + wn * 64 + l15;
#pragma unroll
            for (int nt = 0; nt < 4; nt++) Cp[nt * 16] = acc[mt][nt][r];
        }
    }
}

// ---------------- weight split (W [K x N] fp32 -> B2T [N x KVIRT] bf16) ----------------

__global__ void wsplit_kernel(const float* __restrict__ W, unsigned short* __restrict__ B2T, int N) {
    int idx = blockIdx.x * blockDim.x + threadIdx.x;
    if (idx >= 512 * N) return;
    int k = idx / N, n = idx % N;
    float v = W[(size_t)k * N + n];
    unsigned short hi = bf16_rn(v);
    unsigned short lo = bf16_rn(v - bf16_f32(hi));
    unsigned short* row = B2T + (size_t)n * KVIRT;
    row[k] = hi;
    row[512 + k] = hi;
    row[1024 + k] = lo;
}

// ---------------- x split (fp32 [N_NODES x 512] -> A2 [MPAD x KPHYS]) ----------------

__global__ __launch_bounds__(256) void split_x_kernel(const float* __restrict__ x,
                                                      unsigned short* __restrict__ A2) {
    int m = blockIdx.x;
    int ch = threadIdx.x * 2;
    unsigned short* arow = A2 + (size_t)m * KPHYS;
    float vx = 0.f, vy = 0.f;
    if (m < N_NODES) {
        float2 v = *(const float2*)(x + (size_t)m * 512 + ch);
        vx = v.x;
        vy = v.y;
    }
    unsigned short hx = bf16_rn(vx), hy = bf16_rn(vy);
    arow[ch] = hx;
    arow[ch + 1] = hy;
    arow[512 + ch] = bf16_rn(vx - bf16_f32(hx));
    arow[512 + ch + 1] = bf16_rn(vy - bf16_f32(hy));
}

// ---------------- aggregation ----------------

__device__ __forceinline__ float gelu_tanh(float x) {
    float x3 = x * x * x;
    float inner = 0.7978845608028654f * (x + 0.044715f * x3);
    return 0.5f * x * (1.0f + tanhf(inner));
}

// One node per block, 128 threads, float4 channels (512 ch). Edge list staged in
// LDS (broadcast reads), edges unrolled x4 for memory-level parallelism.
// Output: split-bf16 rows of A2 (feeds next GEMM), bias+gelu fused.
#define ECHUNK 128
__global__ __launch_bounds__(128) void aggregate_split_kernel(
    const float* __restrict__ h, const int* __restrict__ offsets, const int* __restrict__ csr_src,
    const float* __restrict__ csr_w, const float* __restrict__ dinv, const float* __restrict__ bias,
    unsigned short* __restrict__ A2) {
    __shared__ int sm_s[ECHUNK];
    __shared__ float sm_w[ECHUNK];

    int node = blockIdx.x;
    int t = threadIdx.x;
    int ch = t * 4;
    unsigned short* arow = A2 + (size_t)node * KPHYS;
    if (node >= N_NODES) {  // zero pad rows
        *(ushort4*)(arow + ch) = make_ushort4(0, 0, 0, 0);
        *(ushort4*)(arow + 512 + ch) = make_ushort4(0, 0, 0, 0);
        return;
    }
    int p0 = offsets[node], p1 = offsets[node + 1];
    float ax = 0.f, ay = 0.f, az = 0.f, aw = 0.f;

    for (int base = p0; base < p1; base += ECHUNK) {
        int n = p1 - base;
        if (n > ECHUNK) n = ECHUNK;
        __syncthreads();
        if (t < n) {
            sm_s[t] = csr_src[base + t];
            sm_w[t] = csr_w[base + t];
        }
        __syncthreads();
        int j = 0;
        for (; j + 4 <= n; j += 4) {
            int s0 = sm_s[j], s1 = sm_s[j + 1], s2 = sm_s[j + 2], s3 = sm_s[j + 3];
            float w0 = sm_w[j], w1 = sm_w[j + 1], w2 = sm_w[j + 2], w3 = sm_w[j + 3];
            float4 v0 = *(const float4*)(h + (size_t)s0 * 512 + ch);
            float4 v1 = *(const float4*)(h + (size_t)s1 * 512 + ch);
            float4 v2 = *(const float4*)(h + (size_t)s2 * 512 + ch);
            float4 v3 = *(const float4*)(h + (size_t)s3 * 512 + ch);
            ax += w0 * v0.x + w1 * v1.x + w2 * v2.x + w3 * v3.x;
            ay += w0 * v0.y + w1 * v1.y + w2 * v2.y + w3 * v3.y;
            az += w0 * v0.z + w1 * v1.z + w2 * v2.z + w3 * v3.z;
            aw += w0 * v0.w + w1 * v1.w + w2 * v2.w + w3 * v3.w;
        }
        for (; j < n; j++) {
            int s = sm_s[j];
            float wg = sm_w[j];
            float4 v = *(const float4*)(h + (size_t)s * 512 + ch);
            ax += wg * v.x; ay += wg * v.y; az += wg * v.z; aw += wg * v.w;
        }
    }

    float di = dinv[node];
    float wself = di * di;
    float4 hs = *(const float4*)(h + (size_t)node * 512 + ch);
    float4 bv = *(const float4*)(bias + ch);
    ax = gelu_tanh(ax + wself * hs.x + bv.x);
    ay = gelu_tanh(ay + wself * hs.y + bv.y);
    az = gelu_tanh(az + wself * hs.z + bv.z);
    aw = gelu_tanh(aw + wself * hs.w + bv.w);

    unsigned short hx = bf16_rn(ax), hy = bf16_rn(ay), hz = bf16_rn(az), hw = bf16_rn(aw);
    *(ushort4*)(arow + ch) = make_ushort4(hx, hy, hz, hw);
    *(ushort4*)(arow + 512 + ch) =
        make_ushort4(bf16_rn(ax - bf16_f32(hx)), bf16_rn(ay - bf16_f32(hy)),
                     bf16_rn(az - bf16_f32(hz)), bf16_rn(aw - bf16_f32(hw)));
}

// Final agg: 256 ch, one wave per node, float4, fp32 out, no gelu.
__global__ __launch_bounds__(64) void aggregate_final_kernel(
    const float* __restrict__ h, const int* __restrict__ offsets, const int* __restrict__ csr_src,
    const float* __restrict__ csr_w, const float* __restrict__ dinv, const float* __restrict__ bias,
    float* __restrict__ out) {
    __shared__ int sm_s[64];
    __shared__ float sm_w[64];

    int node = blockIdx.x;
    int t = threadIdx.x;
    int ch = t * 4;
    int p0 = offsets[node], p1 = offsets[node + 1];
    float ax = 0.f, ay = 0.f, az = 0.f, aw = 0.f;

    for (int base = p0; base < p1; base += 64) {
        int n = p1 - base;
        if (n > 64) n = 64;
        __syncthreads();
        if (t < n) {
            sm_s[t] = csr_src[base + t];
            sm_w[t] = csr_w[base + t];
        }
        __syncthreads();
        int j = 0;
        for (; j + 4 <= n; j += 4) {
            int s0 = sm_s[j], s1 = sm_s[j + 1], s2 = sm_s[j + 2], s3 = sm_s[j + 3];
            float w0 = sm_w[j], w1 = sm_w[j + 1], w2 = sm_w[j + 2], w3 = sm_w[j + 3];
            float4 v0 = *(const float4*)(h + (size_t)s0 * 256 + ch);
            float4 v1 = *(const float4*)(h + (size_t)s1 * 256 + ch);
            float4 v2 = *(const float4*)(h + (size_t)s2 * 256 + ch);
            float4 v3 = *(const float4*)(h + (size_t)s3 * 256 + ch);
            ax += w0 * v0.x + w1 * v1.x + w2 * v2.x + w3 * v3.x;
            ay += w0 * v0.y + w1 * v1.y + w2 * v2.y + w3 * v3.y;
            az += w0 * v0.z + w1 * v1.z + w2 * v2.z + w3 * v3.z;
            aw += w0 * v0.w + w1 * v1.w + w2 * v2.w + w3 * v3.w;
        }
        for (; j < n; j++) {
            int s = sm_s[j];
            float wg = sm_w[j];
            float4 v = *(const float4*)(h + (size_t)s * 256 + ch);
            ax += wg * v.x; ay += wg * v.y; az += wg * v.z; aw += wg * v.w;
        }
    }

    float di = dinv[node];
    float wself = di * di;
    float4 hs = *(const float4*)(h + (size_t)node * 256 + ch);
    float4 bv = *(const float4*)(bias + ch);
    float4 o = make_float4(ax + wself * hs.x + bv.x, ay + wself * hs.y + bv.y,
                           az + wself * hs.z + bv.z, aw + wself * hs.w + bv.w);
    *(float4*)(out + (size_t)node * 256 + ch) = o;
}

// ---------------- launch ----------------

static inline char* align16(char* p) { return (char*)(((size_t)p + 15) & ~(size_t)15); }

extern "C" void kernel_launch(void* const* d_in, const int* in_sizes, int n_in,
                              void* d_out, int out_size, void* d_ws, size_t ws_size,
                              hipStream_t stream) {
    const float* x  = (const float*)d_in[0];
    const int* eidx = (const int*)d_in[1];
    const float* W1 = (const float*)d_in[2];
    const float* b1 = (const float*)d_in[3];
    const float* W2 = (const float*)d_in[4];
    const float* b2 = (const float*)d_in[5];
    const float* W3 = (const float*)d_in[6];
    const float* b3 = (const float*)d_in[7];
    float* out = (float*)d_out;

    const int* src = eidx;
    const int* dst = eidx + N_EDGES;

    char* ws = (char*)d_ws;
    unsigned short* A2 = (unsigned short*)ws;  ws += (size_t)MPAD * KPHYS * 2;
    float* Cbuf = (float*)ws;                  ws += (size_t)MPAD * 512 * 4;
    unsigned short* B2T1 = (unsigned short*)ws; ws += (size_t)512 * KVIRT * 2;
    unsigned short* B2T2 = (unsigned short*)ws; ws += (size_t)512 * KVIRT * 2;
    unsigned short* B2T3 = (unsigned short*)ws; ws += (size_t)256 * KVIRT * 2;
    int* deg = (int*)ws;        ws = align16(ws + (size_t)N_NODES * 4);
    float* dinv = (float*)ws;   ws = align16(ws + (size_t)N_NODES * 4);
    int* offsets = (int*)ws;    ws = align16(ws + (size_t)(N_NODES + 1) * 4);
    int* cursor = (int*)ws;     ws = align16(ws + (size_t)N_NODES * 4);
    int* csr_src = (int*)ws;    ws = align16(ws + (size_t)N_EDGES * 4);
    float* csr_w = (float*)ws;  ws = align16(ws + (size_t)N_EDGES * 4);

    // ---- CSR build ----
    zero_int_kernel<<<(N_NODES + 255) / 256, 256, 0, stream>>>(deg, N_NODES);
    count_deg_kernel<<<(N_EDGES + 255) / 256, 256, 0, stream>>>(dst, deg);
    dinv_kernel<<<(N_NODES + 255) / 256, 256, 0, stream>>>(deg, dinv);
    scan_kernel<<<1, 1024, 0, stream>>>(deg, offsets, cursor);
    fill_csr_kernel<<<(N_EDGES + 255) / 256, 256, 0, stream>>>(src, dst, cursor, csr_src, csr_w, dinv);

    // ---- weight + input splits ----
    wsplit_kernel<<<(512 * 512 + 255) / 256, 256, 0, stream>>>(W1, B2T1, 512);
    wsplit_kernel<<<(512 * 512 + 255) / 256, 256, 0, stream>>>(W2, B2T2, 512);
    wsplit_kernel<<<(512 * 256 + 255) / 256, 256, 0, stream>>>(W3, B2T3, 256);
    split_x_kernel<<<MPAD, 256, 0, stream>>>(x, A2);

    // ---- layer 1 ----
    {
        dim3 grid(MPAD / 128, 512 / 128);
        gemm_split_bt<<<grid, 256, 0, stream>>>(A2, B2T1, Cbuf, 512);
        aggregate_split_kernel<<<MPAD, 128, 0, stream>>>(Cbuf, offsets, csr_src, csr_w, dinv, b1, A2);
    }
    // ---- layer 2 ----
    {
        dim3 grid(MPAD / 128, 512 / 128);
        gemm_split_bt<<<grid, 256, 0, stream>>>(A2, B2T2, Cbuf, 512);
        aggregate_split_kernel<<<MPAD, 128, 0, stream>>>(Cbuf, offsets, csr_src, csr_w, dinv, b2, A2);
    }
    // ---- layer 3 ----
    {
        dim3 grid(MPAD / 128, 256 / 128);
        gemm_split_bt<<<grid, 256, 0, stream>>>(A2, B2T3, Cbuf, 256);
        aggregate_final_kernel<<<N_NODES, 64, 0, stream>>>(Cbuf, offsets, csr_src, csr_w, dinv, b3, out);
    }
}